// Round 3
// baseline (397.779 us; speedup 1.0000x reference)
//
#include <hip/hip_runtime.h>
#include <cstdint>
#include <cstddef>

typedef _Float16 half8 __attribute__((ext_vector_type(8)));
typedef float floatx4 __attribute__((ext_vector_type(4)));

constexpr int N = 16384;
constexpr int H = 4096;
constexpr int E = 64;
constexpr int BM = 64;           // rows per block
constexpr int BK = 64;           // K per stage
constexpr int NSTAGES = H / BK;  // 64
constexpr float XSCALE = 2048.0f;                      // 2^11
constexpr float WSCALE = 4096.0f;                      // 2^12
constexpr float DESCALE = 1.0f / (2048.0f * 4096.0f);  // 2^-23

// Per-stage buffer (32 KB), double buffered (64 KB total):
//   x   [0,      16384)  64 rows x 256 B, 16B-seg swizzle: phys = log ^ (row&7)
//   Whi [16384,  24576)  64 experts x 128 B, phys = log ^ (e&7)
//   Wlo [24576,  32768)
constexpr int HBOFF = 16384;
constexpr int LBOFF = 24576;
constexpr int BUFSZ = 32768;

__device__ __forceinline__ void async16(const void* g, void* l) {
  __builtin_amdgcn_global_load_lds(
      (const __attribute__((address_space(1))) void*)g,
      (__attribute__((address_space(3))) void*)l,
      16, 0, 0);
}

// ---------------- W split prekernel: W (f32) -> Whi + Wlo (f16), scaled by 2^12
__global__ __launch_bounds__(256) void wsplit_kernel(const float* __restrict__ W,
                                                     _Float16* __restrict__ Whi,
                                                     _Float16* __restrict__ Wlo) {
  int i = blockIdx.x * 256 + threadIdx.x;
  if (i >= E * H) return;
  float w = W[i] * WSCALE;
  _Float16 hi = (_Float16)w;
  _Float16 lo = (_Float16)(w - (float)hi);
  Whi[i] = hi;
  Wlo[i] = lo;
}

// split 8 f32 x-values (scaled by 2^11) into f16 hi/lo fragments
__device__ __forceinline__ void cvt_split(const float4& a, const float4& b,
                                          half8& hi, half8& lo) {
  float f[8] = {a.x, a.y, a.z, a.w, b.x, b.y, b.z, b.w};
#pragma unroll
  for (int i = 0; i < 8; ++i) {
    float s = f[i] * XSCALE;
    _Float16 h = (_Float16)s;
    _Float16 l = (_Float16)(s - (float)h);
    hi[i] = h;
    lo[i] = l;
  }
}

__global__ __launch_bounds__(512, 2) void router_kernel(
    const float* __restrict__ x,
    const _Float16* __restrict__ Whi,
    const _Float16* __restrict__ Wlo,
    float* __restrict__ out_scores,
    float* __restrict__ out_w,
    float* __restrict__ out_i) {
  __shared__ __align__(16) char smem[2 * BUFSZ];

  const int tid = threadIdx.x;
  const int wv = tid >> 6;
  const int lane = tid & 63;
  const int c = lane & 15;
  const int q = lane >> 4;
  const int r0 = blockIdx.x * BM;

  // ---- staging: 4 global_load_lds per thread per stage ----
  // x load l (l=0,1): wave-contiguous dst = l*8192 + tid*16
  //   row = l*32 + 4*wv + (lane>>4), phys seg = lane&15, log = phys ^ (row&7)
  const int xrowA = 4 * wv + q;
  const int xrowB = 32 + xrowA;
  const float* gxA = x + (size_t)(r0 + xrowA) * H + ((c ^ (xrowA & 7)) * 4);
  const float* gxB = x + (size_t)(r0 + xrowB) * H + ((c ^ (xrowB & 7)) * 4);
  // W load: expert e = 8*wv + (lane>>3), phys seg = lane&7, log = phys ^ (e&7)
  const int we = 8 * wv + (lane >> 3);
  const int wlog = (lane & 7) ^ (we & 7);
  const _Float16* gwh = Whi + (size_t)we * H + wlog * 8;
  const _Float16* gwl = Wlo + (size_t)we * H + wlog * 8;
  const int xdstA = tid * 16;
  const int xdstB = 8192 + tid * 16;
  const int wdst = tid * 16;

  // ---- fragment LDS offsets ----
  const int kh = wv >> 2;                 // K-half of stage (0: k 0-31, 1: k 32-63)
  const int rb = (wv & 3) << 4;           // row block 0/16/32/48
  const int fr = rb + c;                  // my A-frag row
  const int sA = 8 * kh + 2 * q;
  const int xo0 = fr * 256 + ((sA ^ (fr & 7)) * 16);
  const int xo1 = fr * 256 + (((sA + 1) ^ (fr & 7)) * 16);
  const int wph = (((4 * kh + q) ^ (c & 7)) * 16);
  const int wo0 = (0 * 16 + c) * 128 + wph;
  const int wo1 = (1 * 16 + c) * 128 + wph;
  const int wo2 = (2 * 16 + c) * 128 + wph;
  const int wo3 = (3 * 16 + c) * 128 + wph;

  auto stage = [&](int s, int b) {
    const int kc = s * BK;
    char* base = smem + b * BUFSZ;
    async16(gxA + kc, base + xdstA);
    async16(gxB + kc, base + xdstB);
    async16(gwh + kc, base + HBOFF + wdst);
    async16(gwl + kc, base + LBOFF + wdst);
  };

  floatx4 acc0 = {0.f, 0.f, 0.f, 0.f};
  floatx4 acc1 = acc0, acc2 = acc0, acc3 = acc0;

  stage(0, 0);
  stage(1, 1);
  for (int s = 0; s < NSTAGES; ++s) {
    const int b = s & 1;
    // wait ONLY this stage's 4 loads (next stage's 4 stay in flight), then barrier
    if (s < NSTAGES - 1) {
      asm volatile("s_waitcnt vmcnt(4)\n\ts_barrier" ::: "memory");
    } else {
      asm volatile("s_waitcnt vmcnt(0)\n\ts_barrier" ::: "memory");
    }

    const char* bb = smem + b * BUFSZ;
    float4 xa = *(const float4*)(bb + xo0);
    float4 xb4 = *(const float4*)(bb + xo1);
    half8 h0 = *(const half8*)(bb + HBOFF + wo0);
    half8 h1 = *(const half8*)(bb + HBOFF + wo1);
    half8 h2 = *(const half8*)(bb + HBOFF + wo2);
    half8 h3 = *(const half8*)(bb + HBOFF + wo3);
    half8 l0 = *(const half8*)(bb + LBOFF + wo0);
    half8 l1 = *(const half8*)(bb + LBOFF + wo1);
    half8 l2 = *(const half8*)(bb + LBOFF + wo2);
    half8 l3 = *(const half8*)(bb + LBOFF + wo3);

    // all frag reads done -> safe for everyone to overwrite this buffer
    asm volatile("s_waitcnt lgkmcnt(0)\n\ts_barrier" ::: "memory");
    if (s + 2 < NSTAGES) stage(s + 2, b);

    half8 ahi, alo;
    cvt_split(xa, xb4, ahi, alo);

    acc0 = __builtin_amdgcn_mfma_f32_16x16x32_f16(alo, h0, acc0, 0, 0, 0);
    acc1 = __builtin_amdgcn_mfma_f32_16x16x32_f16(alo, h1, acc1, 0, 0, 0);
    acc2 = __builtin_amdgcn_mfma_f32_16x16x32_f16(alo, h2, acc2, 0, 0, 0);
    acc3 = __builtin_amdgcn_mfma_f32_16x16x32_f16(alo, h3, acc3, 0, 0, 0);
    acc0 = __builtin_amdgcn_mfma_f32_16x16x32_f16(ahi, l0, acc0, 0, 0, 0);
    acc1 = __builtin_amdgcn_mfma_f32_16x16x32_f16(ahi, l1, acc1, 0, 0, 0);
    acc2 = __builtin_amdgcn_mfma_f32_16x16x32_f16(ahi, l2, acc2, 0, 0, 0);
    acc3 = __builtin_amdgcn_mfma_f32_16x16x32_f16(ahi, l3, acc3, 0, 0, 0);
    acc0 = __builtin_amdgcn_mfma_f32_16x16x32_f16(ahi, h0, acc0, 0, 0, 0);
    acc1 = __builtin_amdgcn_mfma_f32_16x16x32_f16(ahi, h1, acc1, 0, 0, 0);
    acc2 = __builtin_amdgcn_mfma_f32_16x16x32_f16(ahi, h2, acc2, 0, 0, 0);
    acc3 = __builtin_amdgcn_mfma_f32_16x16x32_f16(ahi, h3, acc3, 0, 0, 0);
  }

  // ---- reduce the 2 K-halves via LDS, then per-row softmax/top2 ----
  __syncthreads();
  float* red = (float*)smem;  // [2 kh][64 rows][64 e] = 32 KB
#pragma unroll
  for (int r = 0; r < 4; ++r) {
    const int row = rb + q * 4 + r;
    float* rp = red + (kh * 64 + row) * 64;
    rp[0 * 16 + c] = acc0[r];
    rp[1 * 16 + c] = acc1[r];
    rp[2 * 16 + c] = acc2[r];
    rp[3 * 16 + c] = acc3[r];
  }
  __syncthreads();

  // 8 waves x 8 rows; lane = expert (E == 64 == wave width)
  for (int row = wv * 8; row < wv * 8 + 8; ++row) {
    float v = red[row * 64 + lane] + red[(64 + row) * 64 + lane];
    v *= DESCALE;
    // softmax
    float m = v;
#pragma unroll
    for (int o = 32; o > 0; o >>= 1) m = fmaxf(m, __shfl_xor(m, o));
    float ev = __expf(v - m);
    float ssum = ev;
#pragma unroll
    for (int o = 32; o > 0; o >>= 1) ssum += __shfl_xor(ssum, o);
    out_scores[(size_t)(r0 + row) * E + lane] = ev / ssum;
    // top-2 butterfly with (value desc, index asc) order — matches lax.top_k
    float v1 = v;
    int i1 = lane;
    float v2 = -3.4e38f;
    int i2 = E;
#pragma unroll
    for (int o = 32; o > 0; o >>= 1) {
      float w1 = __shfl_xor(v1, o);
      int j1 = __shfl_xor(i1, o);
      float w2 = __shfl_xor(v2, o);
      int j2 = __shfl_xor(i2, o);
      bool firstBetter = (v1 > w1) || (v1 == w1 && i1 < j1);
      float t1, t2;
      int ti1, ti2;
      if (firstBetter) {
        t1 = v1; ti1 = i1;
        bool sec = (v2 > w1) || (v2 == w1 && i2 < j1);
        t2 = sec ? v2 : w1;
        ti2 = sec ? i2 : j1;
      } else {
        t1 = w1; ti1 = j1;
        bool sec = (w2 > v1) || (w2 == v1 && j2 < i1);
        t2 = sec ? w2 : v1;
        ti2 = sec ? j2 : i1;
      }
      v1 = t1; i1 = ti1; v2 = t2; i2 = ti2;
    }
    if (lane == 0) {
      float e1 = __expf(v1 - m);
      float e2 = __expf(v2 - m);
      float inv = 1.0f / (e1 + e2);
      size_t o2 = (size_t)(r0 + row) * 2;
      out_w[o2] = e1 * inv;
      out_w[o2 + 1] = e2 * inv;
      out_i[o2] = (float)i1;
      out_i[o2 + 1] = (float)i2;
    }
  }
}

extern "C" void kernel_launch(void* const* d_in, const int* in_sizes, int n_in,
                              void* d_out, int out_size, void* d_ws, size_t ws_size,
                              hipStream_t stream) {
  const float* x = (const float*)d_in[0];
  const float* W = (const float*)d_in[1];
  float* out = (float*)d_out;
  float* out_scores = out;                  // [N, 64]
  float* out_w = out + (size_t)N * E;       // [N, 2]
  float* out_i = out_w + (size_t)N * 2;     // [N, 2] (indices as floats)
  _Float16* Whi = (_Float16*)d_ws;
  _Float16* Wlo = Whi + (size_t)E * H;      // 1 MB total in ws

  wsplit_kernel<<<(E * H + 255) / 256, 256, 0, stream>>>(W, Whi, Wlo);
  router_kernel<<<N / BM, 512, 0, stream>>>(x, Whi, Wlo, out_scores, out_w, out_i);
}